// Round 3
// baseline (890.559 us; speedup 1.0000x reference)
//
#include <hip/hip_runtime.h>
#include <hip/hip_bf16.h>
#include <float.h>
#include <math.h>

// MultiScaleReadout — single-pass structure (R3).
// N=500000, D=256, G=1024 (batch sorted), H=L=128.
//   k_prep  : bf16-transpose w1/lp_w; zero the G*897-float accumulator block
//   k_main  : ONE pass over x. Stage x->bf16 LDS (mean/max from fp32 regs),
//             fused MFMA (gate MLP + local MLP), e_i = exp(gate_i) in-block
//             (softmax is shift-invariant; gates are O(0.3) so no overflow),
//             att numerator from bf16 tile. Segment stats via global atomics.
//   k_final : normalize mean/att/local, decode max keys, write [G,896].

typedef __bf16 bf16;
typedef __bf16 bf16x4 __attribute__((ext_vector_type(4)));
typedef __bf16 bf16x8 __attribute__((ext_vector_type(8)));
typedef float f32x4 __attribute__((ext_vector_type(4)));

#define D 256
#define HDIM 128
#define LDIM 128

__device__ __forceinline__ float gelu_f(float v) {
    return 0.5f * v * (1.0f + erff(v * 0.70710678118654752f));
}
// monotone float<->uint key for atomicMax-based float max
__device__ __forceinline__ unsigned fkey(float v) {
    unsigned u = __float_as_uint(v);
    return (u & 0x80000000u) ? ~u : (u | 0x80000000u);
}
__device__ __forceinline__ float funkey(unsigned k) {
    unsigned u = (k & 0x80000000u) ? (k ^ 0x80000000u) : ~k;
    return __uint_as_float(u);
}

// ---------------- Kernel 0: prep ----------------
// zb = [meansum G*256 | attsum G*256 | maxkey G*256 | local G*128 | denom G]
__global__ __launch_bounds__(256) void k_prep(const float* __restrict__ w1,
                                              const float* __restrict__ lpw,
                                              bf16* __restrict__ w1T,
                                              bf16* __restrict__ lpT,
                                              float* __restrict__ zb,
                                              int ztot) {
    int t = blockIdx.x * 256 + threadIdx.x;
    if (t < ztot) zb[t] = 0.0f;   // 0.0f bits == minimum max-key, valid init for all
    if (t < HDIM * D) {
        int n = t >> 8;
        int k = t & 255;
        w1T[t] = (bf16)w1[k * HDIM + n];
        lpT[t] = (bf16)lpw[k * LDIM + n];
    }
}

// ---------------- Kernel 1: the single pass ----------------
__global__ __launch_bounds__(256, 3) void k_main(
    const float* __restrict__ x, const int* __restrict__ batch,
    const bf16* __restrict__ w1T, const float* __restrict__ b1,
    const float* __restrict__ w2, const float* __restrict__ b2,
    const bf16* __restrict__ lpT, const float* __restrict__ lpb,
    float* __restrict__ meansum, float* __restrict__ attsum,
    unsigned* __restrict__ maxkey, float* __restrict__ local_sum,
    float* __restrict__ denom, int N)
{
    __shared__ bf16 xs[64][264];      // +8 pad; reused as float scratch in combine
    __shared__ float earr[64];
    __shared__ float gpart[4][64];
    __shared__ int bs[64];

    const int tid  = threadIdx.x;
    const int wave = tid >> 6;
    const int lane = tid & 63;
    const int quad = lane >> 4;
    const int l16  = lane & 15;
    const int rg   = tid >> 6;        // row group (== wave)
    const int c4   = tid & 63;        // float4 column
    const long base = (long)blockIdx.x * 64;

    const int g0 = batch[base];       // base < N by grid construction
    const bool fast = (base + 63 < N) && (batch[base + 63] == g0);

    if (tid < 64) bs[tid] = (base + tid < N) ? batch[base + tid] : 0x7fffffff;

    // ---- phase 1: stage x -> bf16 LDS; mean/max from fp32 registers ----
    float sacc[4] = {0.f, 0.f, 0.f, 0.f};
    float macc[4] = {-FLT_MAX, -FLT_MAX, -FLT_MAX, -FLT_MAX};
    if (fast) {
        #pragma unroll
        for (int it = 0; it < 16; ++it) {
            int row = rg + it * 4;
            float4 v = *(const float4*)(x + (base + row) * (long)D + c4 * 4);
            bf16x4 pk;
            pk[0] = (bf16)v.x; pk[1] = (bf16)v.y; pk[2] = (bf16)v.z; pk[3] = (bf16)v.w;
            *(bf16x4*)(&xs[row][c4 * 4]) = pk;
            sacc[0] += v.x; sacc[1] += v.y; sacc[2] += v.z; sacc[3] += v.w;
            macc[0] = fmaxf(macc[0], v.x); macc[1] = fmaxf(macc[1], v.y);
            macc[2] = fmaxf(macc[2], v.z); macc[3] = fmaxf(macc[3], v.w);
        }
    } else {
        int rung = -1;
        #pragma unroll
        for (int it = 0; it < 16; ++it) {
            int row = rg + it * 4;
            long node = base + row;
            float4 v = make_float4(0.f, 0.f, 0.f, 0.f);
            if (node < N) v = *(const float4*)(x + node * (long)D + c4 * 4);
            bf16x4 pk;
            pk[0] = (bf16)v.x; pk[1] = (bf16)v.y; pk[2] = (bf16)v.z; pk[3] = (bf16)v.w;
            *(bf16x4*)(&xs[row][c4 * 4]) = pk;
            if (node < N) {
                int gg = batch[node];
                if (gg != rung) {
                    if (rung >= 0) {
                        float* mp = meansum + (long)rung * 256 + c4 * 4;
                        unsigned* kp = maxkey + (long)rung * 256 + c4 * 4;
                        #pragma unroll
                        for (int j = 0; j < 4; ++j) {
                            atomicAdd(mp + j, sacc[j]);
                            atomicMax(kp + j, fkey(macc[j]));
                        }
                    }
                    rung = gg;
                    sacc[0] = sacc[1] = sacc[2] = sacc[3] = 0.f;
                    macc[0] = macc[1] = macc[2] = macc[3] = -FLT_MAX;
                }
                sacc[0] += v.x; sacc[1] += v.y; sacc[2] += v.z; sacc[3] += v.w;
                macc[0] = fmaxf(macc[0], v.x); macc[1] = fmaxf(macc[1], v.y);
                macc[2] = fmaxf(macc[2], v.z); macc[3] = fmaxf(macc[3], v.w);
            }
        }
        if (rung >= 0) {
            float* mp = meansum + (long)rung * 256 + c4 * 4;
            unsigned* kp = maxkey + (long)rung * 256 + c4 * 4;
            #pragma unroll
            for (int j = 0; j < 4; ++j) {
                atomicAdd(mp + j, sacc[j]);
                atomicMax(kp + j, fkey(macc[j]));
            }
        }
    }
    __syncthreads();

    // ---- phase 2: fused MFMA (one A-frag feeds 4 MFMAs) ----
    const int c0 = wave * 32 + l16;
    const int c1 = c0 + 16;
    f32x4 zero = {0.f, 0.f, 0.f, 0.f};
    f32x4 h0[4], h1[4], l0[4], l1[4];
    #pragma unroll
    for (int mt = 0; mt < 4; ++mt) { h0[mt] = zero; h1[mt] = zero; l0[mt] = zero; l1[mt] = zero; }
    #pragma unroll
    for (int kt = 0; kt < 8; ++kt) {
        int k0 = kt * 32 + quad * 8;
        bf16x8 bw0 = *(const bf16x8*)(w1T + c0 * D + k0);
        bf16x8 bw1 = *(const bf16x8*)(w1T + c1 * D + k0);
        bf16x8 bp0 = *(const bf16x8*)(lpT + c0 * D + k0);
        bf16x8 bp1 = *(const bf16x8*)(lpT + c1 * D + k0);
        #pragma unroll
        for (int mt = 0; mt < 4; ++mt) {
            bf16x8 a = *(const bf16x8*)(&xs[mt * 16 + l16][k0]);
            h0[mt] = __builtin_amdgcn_mfma_f32_16x16x32_bf16(a, bw0, h0[mt], 0, 0, 0);
            h1[mt] = __builtin_amdgcn_mfma_f32_16x16x32_bf16(a, bw1, h1[mt], 0, 0, 0);
            l0[mt] = __builtin_amdgcn_mfma_f32_16x16x32_bf16(a, bp0, l0[mt], 0, 0, 0);
            l1[mt] = __builtin_amdgcn_mfma_f32_16x16x32_bf16(a, bp1, l1[mt], 0, 0, 0);
        }
    }

    // ---- phase 3: gate row values ----
    {
        const float b1c0 = b1[c0], b1c1 = b1[c1];
        const float w2c0 = w2[c0], w2c1 = w2[c1];
        #pragma unroll
        for (int mt = 0; mt < 4; ++mt) {
            #pragma unroll
            for (int r = 0; r < 4; ++r) {
                float v = gelu_f(h0[mt][r] + b1c0) * w2c0
                        + gelu_f(h1[mt][r] + b1c1) * w2c1;
                v += __shfl_down(v, 8, 16);
                v += __shfl_down(v, 4, 16);
                v += __shfl_down(v, 2, 16);
                v += __shfl_down(v, 1, 16);
                if (l16 == 0) gpart[wave][mt * 16 + quad * 4 + r] = v;
            }
        }
    }
    __syncthreads();
    if (tid < 64) {
        long node = base + tid;
        float gv = gpart[0][tid] + gpart[1][tid] + gpart[2][tid] + gpart[3][tid] + b2[0];
        // shift-free softmax weight: exact ratio; gates are O(0.3), no overflow risk
        float e = (node < N) ? expf(gv) : 0.f;
        earr[tid] = e;
        if (fast) {
            float t = e;
            t += __shfl_xor(t, 1);  t += __shfl_xor(t, 2);  t += __shfl_xor(t, 4);
            t += __shfl_xor(t, 8);  t += __shfl_xor(t, 16); t += __shfl_xor(t, 32);
            if (tid == 0) atomicAdd(&denom[g0], t);
        } else if (node < N) {
            atomicAdd(&denom[bs[tid]], e);
        }
    }
    __syncthreads();

    // ---- phase 4: local MLP segment sums (from l accs) ----
    {
        const float lb0 = lpb[c0], lb1 = lpb[c1];
        if (fast) {
            float s0 = 0.f, s1 = 0.f;
            #pragma unroll
            for (int mt = 0; mt < 4; ++mt) {
                #pragma unroll
                for (int r = 0; r < 4; ++r) {
                    s0 += gelu_f(l0[mt][r] + lb0);
                    s1 += gelu_f(l1[mt][r] + lb1);
                }
            }
            s0 += __shfl_xor(s0, 16); s0 += __shfl_xor(s0, 32);
            s1 += __shfl_xor(s1, 16); s1 += __shfl_xor(s1, 32);
            if (quad == 0) {
                atomicAdd(&local_sum[(long)g0 * LDIM + c0], s0);
                atomicAdd(&local_sum[(long)g0 * LDIM + c1], s1);
            }
        } else {
            int cur = -1;
            float s0 = 0.f, s1 = 0.f;
            #pragma unroll
            for (int mt = 0; mt < 4; ++mt) {
                #pragma unroll
                for (int r = 0; r < 4; ++r) {
                    int lrow = mt * 16 + quad * 4 + r;
                    if (base + lrow < N) {
                        int gg = bs[lrow];
                        if (gg != cur) {
                            if (cur >= 0) {
                                atomicAdd(&local_sum[(long)cur * LDIM + c0], s0);
                                atomicAdd(&local_sum[(long)cur * LDIM + c1], s1);
                            }
                            cur = gg; s0 = 0.f; s1 = 0.f;
                        }
                        s0 += gelu_f(l0[mt][r] + lb0);
                        s1 += gelu_f(l1[mt][r] + lb1);
                    }
                }
            }
            if (cur >= 0) {
                atomicAdd(&local_sum[(long)cur * LDIM + c0], s0);
                atomicAdd(&local_sum[(long)cur * LDIM + c1], s1);
            }
        }
    }

    // ---- phase 5: attention numerator from bf16 tile ----
    float aacc[4] = {0.f, 0.f, 0.f, 0.f};
    if (fast) {
        #pragma unroll
        for (int it = 0; it < 16; ++it) {
            int row = rg + it * 4;
            float e = earr[row];
            bf16x4 pv = *(const bf16x4*)(&xs[row][c4 * 4]);
            aacc[0] += e * (float)pv[0]; aacc[1] += e * (float)pv[1];
            aacc[2] += e * (float)pv[2]; aacc[3] += e * (float)pv[3];
        }
    } else {
        int rung = -1;
        #pragma unroll
        for (int it = 0; it < 16; ++it) {
            int row = rg + it * 4;
            if (base + row >= N) break;
            int gg = bs[row];
            if (gg != rung) {
                if (rung >= 0) {
                    float* ap = attsum + (long)rung * 256 + c4 * 4;
                    #pragma unroll
                    for (int j = 0; j < 4; ++j) atomicAdd(ap + j, aacc[j]);
                }
                rung = gg;
                aacc[0] = aacc[1] = aacc[2] = aacc[3] = 0.f;
            }
            float e = earr[row];
            bf16x4 pv = *(const bf16x4*)(&xs[row][c4 * 4]);
            aacc[0] += e * (float)pv[0]; aacc[1] += e * (float)pv[1];
            aacc[2] += e * (float)pv[2]; aacc[3] += e * (float)pv[3];
        }
        if (rung >= 0) {
            float* ap = attsum + (long)rung * 256 + c4 * 4;
            #pragma unroll
            for (int j = 0; j < 4; ++j) atomicAdd(ap + j, aacc[j]);
        }
    }
    __syncthreads();   // all xs reads complete

    // ---- phase 6 (fast only): LDS partial reduce -> 3 atomics per column ----
    if (fast) {
        float* xsf = (float*)&xs[0][0];   // reuse: need 3*4*256 floats = 12 KB
        #pragma unroll
        for (int j = 0; j < 4; ++j) {
            int c = c4 * 4 + j;
            xsf[rg * 256 + c]        = sacc[j];
            xsf[1024 + rg * 256 + c] = macc[j];
            xsf[2048 + rg * 256 + c] = aacc[j];
        }
        __syncthreads();
        int c = tid;
        float s = xsf[c] + xsf[256 + c] + xsf[512 + c] + xsf[768 + c];
        float m = fmaxf(fmaxf(xsf[1024 + c], xsf[1280 + c]),
                        fmaxf(xsf[1536 + c], xsf[1792 + c]));
        float a = xsf[2048 + c] + xsf[2304 + c] + xsf[2560 + c] + xsf[2816 + c];
        atomicAdd(&meansum[(long)g0 * 256 + c], s);
        atomicMax(&maxkey[(long)g0 * 256 + c], fkey(m));
        atomicAdd(&attsum[(long)g0 * 256 + c], a);
    }
}

// ---------------- Kernel 2: finalize ----------------
__device__ __forceinline__ int lower_bound_i(const int* a, int n, int v) {
    int lo = 0, hi = n;
    while (lo < hi) { int mid = (lo + hi) >> 1; if (a[mid] < v) lo = mid + 1; else hi = mid; }
    return lo;
}

__global__ __launch_bounds__(256) void k_final(
    const int* __restrict__ batch,
    const float* __restrict__ meansum, const float* __restrict__ attsum,
    const unsigned* __restrict__ maxkey, const float* __restrict__ local_sum,
    const float* __restrict__ denom, float* __restrict__ out, int N)
{
    const int g   = blockIdx.x;
    const int tid = threadIdx.x;
    __shared__ int sse[2];
    if (tid == 0) sse[0] = lower_bound_i(batch, N, g);
    if (tid == 1) sse[1] = lower_bound_i(batch, N, g + 1);
    __syncthreads();
    const int cnt = sse[1] - sse[0];
    const float inv = 1.0f / fmaxf((float)cnt, 1.0f);
    const float dn  = denom[g];
    const float invd = (dn > 0.f) ? 1.0f / dn : 0.f;
    const long o = (long)g * 896;

    out[o + tid]       = meansum[(long)g * 256 + tid] * inv;
    out[o + 256 + tid] = (cnt == 0) ? -INFINITY : funkey(maxkey[(long)g * 256 + tid]);
    out[o + 512 + tid] = attsum[(long)g * 256 + tid] * invd;
    if (tid < 128) out[o + 768 + tid] = local_sum[(long)g * LDIM + tid] * inv;
}

// ---------------- launch ----------------
extern "C" void kernel_launch(void* const* d_in, const int* in_sizes, int n_in,
                              void* d_out, int out_size, void* d_ws, size_t ws_size,
                              hipStream_t stream) {
    const float* x   = (const float*)d_in[0];
    const int* batch = (const int*)d_in[1];
    const float* w1  = (const float*)d_in[2];
    const float* b1  = (const float*)d_in[3];
    const float* w2  = (const float*)d_in[4];
    const float* b2  = (const float*)d_in[5];
    const float* lpw = (const float*)d_in[6];
    const float* lpb = (const float*)d_in[7];
    float* out = (float*)d_out;

    const int N = in_sizes[0] / D;
    const int G = out_size / 896;

    char* ws = (char*)d_ws;
    size_t off = 0;
    const int ztot = G * (256 + 256 + 256 + 128 + 1);   // 897 floats per segment
    float* zb = (float*)(ws + off); off += (((size_t)ztot * 4) + 255) & ~(size_t)255;
    bf16* w1T = (bf16*)(ws + off);  off += (size_t)HDIM * D * 2;
    bf16* lpT = (bf16*)(ws + off);  off += (size_t)LDIM * D * 2;

    float*    meansum   = zb;
    float*    attsum    = zb + (size_t)G * 256;
    unsigned* maxkey    = (unsigned*)(zb + (size_t)2 * G * 256);
    float*    local_sum = zb + (size_t)3 * G * 256;
    float*    denom     = zb + (size_t)3 * G * 256 + (size_t)G * 128;

    k_prep<<<(ztot + 255) / 256, 256, 0, stream>>>(w1, lpw, w1T, lpT, zb, ztot);
    k_main<<<(int)((N + 63) / 64), 256, 0, stream>>>(x, batch, w1T, b1, w2, b2, lpT, lpb,
                                                     meansum, attsum, maxkey, local_sum,
                                                     denom, N);
    k_final<<<G, 256, 0, stream>>>(batch, meansum, attsum, maxkey, local_sum, denom, out, N);
}